// Round 1
// baseline (12040.964 us; speedup 1.0000x reference)
//
#include <hip/hip_runtime.h>
#include <hip/hip_bf16.h>
#include <cstdint>
#include <cstddef>

#define NB   131072   // items
#define ED   256      // e_dim
#define NQL  4        // quantizer levels
#define NEC  256      // codebook entries

static constexpr int BMI  = 32;    // items per block
static constexpr int BKC  = 16;    // K-chunk
static constexpr int RPAD = 260;   // padded LDS row stride (floats), 16B-aligned, rotates banks by 4/row

static constexpr size_t OFF_REC  = (size_t)NB * ED;        // rec_x_q
static constexpr size_t OFF_LOSS = 2 * (size_t)NB * ED;    // scalar loss
static constexpr size_t OFF_SIDX = OFF_LOSS + 1;           // src_idx [B,4]
static constexpr size_t OFF_RIDX = OFF_SIDX + (size_t)NB * NQL;

// workspace layout (bytes)
static constexpr size_t WS_LOSS = 0;                       // 8 doubles
static constexpr size_t WS_NORM = 256;                     // 8*256 floats
static constexpr size_t WS_CBT  = 256 + 8 * 256 * 4;       // 8448; 8*256*256 floats
static constexpr size_t WS_NEED_CBT = WS_CBT + (size_t)8 * 256 * 256 * 4;

// ---- prep: zero loss accumulators + codebook row norms ----
__global__ void kPrep(const float* __restrict__ cbS, const float* __restrict__ cbR,
                      float* __restrict__ norms, double* __restrict__ lossAcc) {
  const int cbi = blockIdx.x;    // 0..7 = branch*4+level
  const int j   = threadIdx.x;   // 0..255
  if (cbi == 0 && j < 8) lossAcc[j] = 0.0;
  const float* row = (cbi < 4 ? cbS : cbR) + ((size_t)(cbi & 3) * NEC + j) * ED;
  float acc = 0.f;
  for (int k = 0; k < ED; k += 4) {
    float4 v = *(const float4*)(row + k);
    acc += v.x * v.x + v.y * v.y + v.z * v.z + v.w * v.w;
  }
  norms[cbi * NEC + j] = acc;
}

// ---- transpose codebooks into ws: cbT[cbi][k][j] = cb[cbi][j][k] ----
__global__ void kTrans(const float* __restrict__ cbS, const float* __restrict__ cbR,
                       float* __restrict__ cbT) {
  const int f   = blockIdx.x * 256 + threadIdx.x;   // 0..524287
  const int cbi = f >> 16;
  const int rem = f & 65535;
  const int k   = rem >> 8;
  const int j   = rem & 255;
  const float* cb = (cbi < 4 ? cbS : cbR) + ((size_t)(cbi & 3) << 16);
  cbT[(size_t)f] = cb[j * NEC + k];   // coalesced write, strided read
}

// ---- main fused RVQ kernel ----
template <bool USE_CBT>
__global__ __launch_bounds__(256, 3)
void kMain(const float* __restrict__ x,
           const float* __restrict__ cbS,
           const float* __restrict__ cbR,
           const float* __restrict__ cbT,
           const float* __restrict__ norms,
           double* __restrict__ lossAcc,
           float* __restrict__ out) {
  __shared__ float res[BMI * RPAD];     // fp32 residual, [item][k] padded
  __shared__ float cbs[BKC * RPAD];     // codebook K-chunk, [k][j] padded
  __shared__ float normS[NEC];
  __shared__ int   jminS[BMI];
  __shared__ float red[4];

  const int tid = threadIdx.x;
  const int ty  = tid >> 4;     // 0..15 -> items ty*2..+1
  const int tx  = tid & 15;     // 0..15 -> codewords tx*16..+15
  const int b0  = blockIdx.x * BMI;
  const int iu  = tid >> 3;     // 0..31 item for elementwise passes
  const int kg  = tid & 7;      // 0..7 k-group (32 floats)

#pragma unroll 1
  for (int br = 0; br < 2; ++br) {
    const float* cbbase = br ? cbR : cbS;

    // load residual = x[:, br*E : br*E+E]
    {
      const float* xrow = x + (size_t)(b0 + iu) * (2 * ED) + br * ED + kg * 32;
#pragma unroll
      for (int kk = 0; kk < 8; ++kk) {
        float4 v = *(const float4*)(xrow + kk * 4);
        *(float4*)&res[iu * RPAD + kg * 32 + kk * 4] = v;
      }
    }

#pragma unroll 1
    for (int lev = 0; lev < NQL; ++lev) {
      const int cbi = br * 4 + lev;
      normS[tid] = norms[cbi * NEC + tid];
      __syncthreads();   // also orders res writes (load/update) before GEMM reads

      float acc[2][16];
#pragma unroll
      for (int m = 0; m < 2; ++m)
#pragma unroll
        for (int n = 0; n < 16; ++n) acc[m][n] = 0.f;

#pragma unroll 1
      for (int k0 = 0; k0 < ED; k0 += BKC) {
        // stage codebook chunk [k0..k0+15][0..255] into LDS
        if constexpr (USE_CBT) {
          const float* src = cbT + ((size_t)cbi << 16) + (size_t)k0 * NEC + tid;
#pragma unroll
          for (int r = 0; r < BKC; ++r)
            cbs[r * RPAD + tid] = src[(size_t)r * NEC];
        } else {
          const float* row = cbbase + ((size_t)lev * NEC + tid) * ED + k0;
          float4 v[4];
#pragma unroll
          for (int q = 0; q < 4; ++q) v[q] = *(const float4*)(row + 4 * q);
#pragma unroll
          for (int q = 0; q < 4; ++q) {
            cbs[(4 * q + 0) * RPAD + tid] = v[q].x;
            cbs[(4 * q + 1) * RPAD + tid] = v[q].y;
            cbs[(4 * q + 2) * RPAD + tid] = v[q].z;
            cbs[(4 * q + 3) * RPAD + tid] = v[q].w;
          }
        }
        __syncthreads();

        // a-fragments for this chunk
        float ar[2][BKC];
#pragma unroll
        for (int m = 0; m < 2; ++m) {
#pragma unroll
          for (int q = 0; q < BKC; q += 4) {
            float4 v = *(const float4*)&res[(ty * 2 + m) * RPAD + k0 + q];
            ar[m][q] = v.x; ar[m][q + 1] = v.y; ar[m][q + 2] = v.z; ar[m][q + 3] = v.w;
          }
        }

#pragma unroll
        for (int kk = 0; kk < BKC; ++kk) {
          float b[16];
#pragma unroll
          for (int n = 0; n < 16; n += 4) {
            float4 v = *(const float4*)&cbs[kk * RPAD + tx * 16 + n];
            b[n] = v.x; b[n + 1] = v.y; b[n + 2] = v.z; b[n + 3] = v.w;
          }
#pragma unroll
          for (int m = 0; m < 2; ++m)
#pragma unroll
            for (int n = 0; n < 16; ++n)
              acc[m][n] = fmaf(ar[m][kk], b[n], acc[m][n]);
        }
        __syncthreads();
      }

      // argmin_j (||c||^2 - 2 s), first-min tie-break (np argmin semantics)
      float best[2]; int bj[2];
#pragma unroll
      for (int m = 0; m < 2; ++m) {
        best[m] = 3.402823466e+38f; bj[m] = 0;
#pragma unroll
        for (int n = 0; n < 16; ++n) {
          const int j = tx * 16 + n;
          const float t = normS[j] - 2.f * acc[m][n];
          if (t < best[m]) { best[m] = t; bj[m] = j; }
        }
      }
#pragma unroll
      for (int off = 1; off < 16; off <<= 1) {
#pragma unroll
        for (int m = 0; m < 2; ++m) {
          const float ob = __shfl_xor(best[m], off, 64);
          const int   oj = __shfl_xor(bj[m], off, 64);
          if (ob < best[m] || (ob == best[m] && oj < bj[m])) { best[m] = ob; bj[m] = oj; }
        }
      }
      if (tx == 0) {
#pragma unroll
        for (int m = 0; m < 2; ++m) {
          const int item = ty * 2 + m;
          jminS[item] = bj[m];
          const size_t ioff = (br ? OFF_RIDX : OFF_SIDX) + (size_t)(b0 + item) * NQL + lev;
          out[ioff] = (float)bj[m];  // indices emitted as f32
        }
      }
      __syncthreads();

      // residual update + loss (elementwise, matching reference rounding chain)
      float lacc = 0.f;
      {
        const int jm = jminS[iu];
        const float* crow = cbbase + ((size_t)lev * NEC + jm) * ED + kg * 32;
#pragma unroll
        for (int kk = 0; kk < 8; ++kk) {
          float4 q = *(const float4*)(crow + kk * 4);
          float* rp = &res[iu * RPAD + kg * 32 + kk * 4];
          float4 r = *(float4*)rp;
          const float dx = q.x - r.x, dy = q.y - r.y, dz = q.z - r.z, dw = q.w - r.w;
          lacc += dx * dx; lacc += dy * dy; lacc += dz * dz; lacc += dw * dw;
          float4 xr; xr.x = r.x + dx; xr.y = r.y + dy; xr.z = r.z + dz; xr.w = r.w + dw;
          float4 rn; rn.x = r.x - xr.x; rn.y = r.y - xr.y; rn.z = r.z - xr.z; rn.w = r.w - xr.w;
          *(float4*)rp = rn;
        }
      }
#pragma unroll
      for (int off = 1; off < 64; off <<= 1) lacc += __shfl_xor(lacc, off, 64);
      if ((tid & 63) == 0) red[tid >> 6] = lacc;
      __syncthreads();
      if (tid == 0) atomicAdd(&lossAcc[cbi], (double)((red[0] + red[1]) + (red[2] + red[3])));
      __syncthreads();
    }

    // x_q = x - residual_final
    {
      const float* xrow = x + (size_t)(b0 + iu) * (2 * ED) + br * ED + kg * 32;
      float* orow = out + (br ? OFF_REC : 0) + (size_t)(b0 + iu) * ED + kg * 32;
#pragma unroll
      for (int kk = 0; kk < 8; ++kk) {
        float4 xv = *(const float4*)(xrow + kk * 4);
        float4 r  = *(float4*)&res[iu * RPAD + kg * 32 + kk * 4];
        float4 o; o.x = xv.x - r.x; o.y = xv.y - r.y; o.z = xv.z - r.z; o.w = xv.w - r.w;
        *(float4*)(orow + kk * 4) = o;
      }
    }
    __syncthreads();  // res reused by next branch
  }
}

// ---- finalize scalar loss ----
__global__ void kFin(const double* __restrict__ lossAcc, float* __restrict__ out) {
  if (blockIdx.x == 0 && threadIdx.x == 0) {
    double s = 0.0;
    for (int l = 0; l < 8; ++l) s += lossAcc[l];
    // per-level loss = (1+beta)*S_l/(B*E); mean over 8 levels
    out[OFF_LOSS] = (float)(s * 1.25 / ((double)NB * ED) / 8.0);
  }
}

extern "C" void kernel_launch(void* const* d_in, const int* in_sizes, int n_in,
                              void* d_out, int out_size, void* d_ws, size_t ws_size,
                              hipStream_t stream) {
  const float* x   = (const float*)d_in[0];
  const float* cbS = (const float*)d_in[1];
  const float* cbR = (const float*)d_in[2];
  float* out = (float*)d_out;
  char*  ws  = (char*)d_ws;

  double* lossAcc = (double*)(ws + WS_LOSS);
  float*  norms   = (float*)(ws + WS_NORM);
  float*  cbT     = (float*)(ws + WS_CBT);
  const bool useCbT = (ws_size >= WS_NEED_CBT);

  hipLaunchKernelGGL(kPrep, dim3(8), dim3(256), 0, stream, cbS, cbR, norms, lossAcc);
  if (useCbT) {
    hipLaunchKernelGGL(kTrans, dim3(2048), dim3(256), 0, stream, cbS, cbR, cbT);
    hipLaunchKernelGGL((kMain<true>), dim3(NB / BMI), dim3(256), 0, stream,
                       x, cbS, cbR, cbT, norms, lossAcc, out);
  } else {
    hipLaunchKernelGGL((kMain<false>), dim3(NB / BMI), dim3(256), 0, stream,
                       x, cbS, cbR, cbT, norms, lossAcc, out);
  }
  hipLaunchKernelGGL(kFin, dim3(1), dim3(64), 0, stream, lossAcc, out);
}

// Round 2
// 712.419 us; speedup vs baseline: 16.9015x; 16.9015x over previous
//
#include <hip/hip_runtime.h>
#include <hip/hip_bf16.h>
#include <hip/hip_fp16.h>
#include <cstdint>
#include <cstddef>

#define NB   131072   // items
#define ED   256      // e_dim
#define NQL  4        // levels
#define NEC  256      // codebook entries

typedef _Float16 f16;
typedef f16  f16x8 __attribute__((ext_vector_type(8)));
typedef float f32x4 __attribute__((ext_vector_type(4)));

static constexpr float FMAXV = 3.402823466e+38f;
static constexpr float TAU   = 0.15625f;   // rescore gate on approx top-2 gap

static constexpr size_t OFF_REC  = (size_t)NB * ED;
static constexpr size_t OFF_LOSS = 2 * (size_t)NB * ED;
static constexpr size_t OFF_SIDX = OFF_LOSS + 1;
static constexpr size_t OFF_RIDX = OFF_SIDX + (size_t)NB * NQL;

// workspace layout (bytes)
static constexpr size_t WS_LOSS = 0;                      // 8 doubles
static constexpr size_t WS_NORM = 256;                    // 8*256 f32
static constexpr size_t WS_CBH  = 256 + 8 * 256 * 4;      // 8448; 8*256*256 f16 (1 MB)

// ---- prep: zero loss accumulators + codebook row norms (fp32, same as passing round) ----
__global__ void kPrep(const float* __restrict__ cbS, const float* __restrict__ cbR,
                      float* __restrict__ norms, double* __restrict__ lossAcc) {
  const int cbi = blockIdx.x;    // 0..7
  const int j   = threadIdx.x;   // 0..255
  if (cbi == 0 && j < 8) lossAcc[j] = 0.0;
  const float* row = (cbi < 4 ? cbS : cbR) + ((size_t)(cbi & 3) * NEC + j) * ED;
  float acc = 0.f;
  for (int k = 0; k < ED; k += 4) {
    float4 v = *(const float4*)(row + k);
    acc += v.x * v.x + v.y * v.y + v.z * v.z + v.w * v.w;
  }
  norms[cbi * NEC + j] = acc;
}

// ---- f16 copy of codebooks (natural [cbi][j][k] layout) ----
__global__ void kConvH(const float* __restrict__ cbS, const float* __restrict__ cbR,
                       f16* __restrict__ cbH) {
  const int f   = blockIdx.x * 256 + threadIdx.x;   // 0..524287
  const int cbi = f >> 16;
  const int rem = f & 65535;
  const float v = (cbi < 4 ? cbS + ((size_t)cbi << 16) : cbR + ((size_t)(cbi - 4) << 16))[rem];
  cbH[f] = (f16)v;   // RTN
}

// packed key helpers: low 8 mantissa bits carry the codeword index
__device__ __forceinline__ float pk(float v, int j) {
  return __uint_as_float((__float_as_uint(v) & ~255u) | (unsigned)j);
}
__device__ __forceinline__ float unpv(float k) {
  return __uint_as_float(__float_as_uint(k) & ~255u);
}
__device__ __forceinline__ void ins3(float& s0, float& s1, float& s2, float k) {
  float t0 = fmaxf(s0, k); s0 = fminf(s0, k);
  float t1 = fmaxf(s1, t0); s1 = fminf(s1, t0);
  s2 = fminf(s2, t1);
}
__device__ __forceinline__ void mrg3(float& a0, float& a1, float& a2,
                                     float b0, float b1, float b2) {
  float x  = fmaxf(a0, b0);
  float c0 = fminf(a0, b0);
  float m1 = fminf(a1, b1), M1 = fmaxf(a1, b1);
  float c1 = fminf(fminf(x, a1), b1);
  float c2 = fminf(fminf(fmaxf(x, m1), M1), fminf(a2, b2));
  a0 = c0; a1 = c1; a2 = c2;
}

// ---- main fused RVQ kernel: 64 items/block, res in registers ----
__global__ __launch_bounds__(256, 2)
void kMain(const float* __restrict__ x,
           const float* __restrict__ cbS,
           const float* __restrict__ cbR,
           const f16*  __restrict__ cbH,
           const float* __restrict__ norms,
           double* __restrict__ lossAcc,
           float* __restrict__ out) {
  __shared__ __align__(16) char  RhBuf[64 * 512];      // f16 residual image, swizzled
  __shared__ __align__(16) float keybuf[64][17][4];    // quad top-3 (padded)
  __shared__ float nrmAdj[NEC];                        // norm - 256 (exact shift)
  __shared__ int   jminS[64];
  __shared__ int   candS[64];
  __shared__ int   flagAny;
  __shared__ float redS[4];

  const int tid   = threadIdx.x;
  const int lane  = tid & 63;
  const int w     = tid >> 6;       // wave: owns codewords [64w, 64w+64)
  const int it_o  = tid >> 2;       // owner item 0..63
  const int kq    = tid & 3;        // owner k-quarter
  const int b0    = blockIdx.x * 64;
  const int l15   = lane & 15;
  const int l4    = lane >> 4;

  float res[64];

#pragma unroll 1
  for (int br = 0; br < 2; ++br) {
    const float* cbf32 = br ? cbR : cbS;

    // load residual = x[:, br*E .. br*E+E) slice into registers
    {
      const float* xp = x + (size_t)(b0 + it_o) * (2 * ED) + br * ED + kq * 64;
#pragma unroll
      for (int i = 0; i < 16; ++i) {
        float4 v = *(const float4*)(xp + 4 * i);
        res[4 * i + 0] = v.x; res[4 * i + 1] = v.y;
        res[4 * i + 2] = v.z; res[4 * i + 3] = v.w;
      }
    }

#pragma unroll 1
    for (int lev = 0; lev < NQL; ++lev) {
      const int cbi = br * 4 + lev;
      nrmAdj[tid] = norms[cbi * NEC + tid] - 256.0f;   // exact (Sterbenz)

      // convert res -> Rh (f16, RTN), swizzled rows of 512B
#pragma unroll
      for (int c = 0; c < 8; ++c) {
        f16x8 h;
#pragma unroll
        for (int u = 0; u < 8; ++u) h[u] = (f16)res[c * 8 + u];
        int off = it_o * 512 + kq * 128 + c * 16;
        off ^= (it_o & 7) << 4;
        *(f16x8*)&RhBuf[off] = h;
      }
      __syncthreads();

      // ---- GEMM: acc[mt][nt] = R . C^T for this wave's 64 codewords ----
      f32x4 acc[4][4];
#pragma unroll
      for (int mt = 0; mt < 4; ++mt)
#pragma unroll
        for (int nt = 0; nt < 4; ++nt) { f32x4 z = {0.f, 0.f, 0.f, 0.f}; acc[mt][nt] = z; }

      const f16* cbh = cbH + ((size_t)cbi << 16);
#pragma unroll
      for (int ks = 0; ks < 8; ++ks) {
        f16x8 A[4], B[4];
#pragma unroll
        for (int mt = 0; mt < 4; ++mt) {
          int it  = mt * 16 + l15;
          int off = it * 512 + ks * 64 + l4 * 16;
          off ^= (it & 7) << 4;
          A[mt] = *(const f16x8*)&RhBuf[off];
        }
#pragma unroll
        for (int nt = 0; nt < 4; ++nt) {
          int j = (w * 4 + nt) * 16 + l15;
          B[nt] = *(const f16x8*)&cbh[(size_t)j * ED + ks * 32 + l4 * 8];
        }
#pragma unroll
        for (int mt = 0; mt < 4; ++mt)
#pragma unroll
          for (int nt = 0; nt < 4; ++nt)
            acc[mt][nt] = __builtin_amdgcn_mfma_f32_16x16x32_f16(A[mt], B[nt], acc[mt][nt], 0, 0, 0);
      }

      // ---- keys + quad top-3 (packed index in mantissa low bits) ----
      float nv[4];
#pragma unroll
      for (int nt = 0; nt < 4; ++nt) nv[nt] = nrmAdj[(w * 4 + nt) * 16 + l15];

#pragma unroll
      for (int mt = 0; mt < 4; ++mt) {
#pragma unroll
        for (int r = 0; r < 4; ++r) {
          float s0 = FMAXV, s1 = FMAXV, s2 = FMAXV;
#pragma unroll
          for (int nt = 0; nt < 4; ++nt) {
            int j = (w * 4 + nt) * 16 + l15;
            float key = pk(fmaf(-2.f, acc[mt][nt][r], nv[nt]), j);
            ins3(s0, s1, s2, key);
          }
          // butterfly within quad (lanes xor 1, 2): same item, j-parts differ
          {
            float b0k = __shfl_xor(s0, 1), b1k = __shfl_xor(s1, 1), b2k = __shfl_xor(s2, 1);
            mrg3(s0, s1, s2, b0k, b1k, b2k);
            b0k = __shfl_xor(s0, 2); b1k = __shfl_xor(s1, 2); b2k = __shfl_xor(s2, 2);
            mrg3(s0, s1, s2, b0k, b1k, b2k);
          }
          if ((lane & 3) == 0) {
            int item = mt * 16 + l4 * 4 + r;
            int qg   = w * 4 + ((lane >> 2) & 3);
            float4 v; v.x = s0; v.y = s1; v.z = s2; v.w = FMAXV;
            *(float4*)&keybuf[item][qg][0] = v;
          }
        }
      }
      __syncthreads();

      // ---- final merge: wave 0, one thread per item ----
      if (tid < 64) {
        float s0 = FMAXV, s1 = FMAXV, s2 = FMAXV;
#pragma unroll
        for (int q = 0; q < 16; ++q) {
          float4 v = *(const float4*)&keybuf[tid][q][0];
          ins3(s0, s1, s2, v.x); ins3(s0, s1, s2, v.y); ins3(s0, s1, s2, v.z);
        }
        int j0 = (int)(__float_as_uint(s0) & 255u);
        int j1 = (int)(__float_as_uint(s1) & 255u);
        int j2 = (int)(__float_as_uint(s2) & 255u);
        float gap = unpv(s1) - unpv(s0);
        bool flag = (gap < TAU);
        unsigned long long bal = __ballot(flag);
        if (tid == 0) flagAny = (bal != 0ull) ? 1 : 0;
        jminS[tid] = j0;
        candS[tid] = flag ? (j0 | (j1 << 8) | (j2 << 16) | (1 << 24)) : 0;
        if (!flag) {
          const size_t ioff = (br ? OFF_RIDX : OFF_SIDX) + (size_t)(b0 + tid) * NQL + lev;
          out[ioff] = (float)j0;
        }
      }
      __syncthreads();

      // ---- gated exact fp32 rescore of top-3 (owner quad per item) ----
      if (flagAny) {
        int c = candS[it_o];
        if (c & (1 << 24)) {
          float bestd = FMAXV; int bestj = 0;
#pragma unroll 1
          for (int cc = 0; cc < 3; ++cc) {
            int j = (c >> (8 * cc)) & 255;
            const float* row = cbf32 + ((size_t)lev * NEC + j) * ED + kq * 64;
            float p = 0.f;
#pragma unroll
            for (int i = 0; i < 16; ++i) {
              float4 q = *(const float4*)(row + 4 * i);
              p = fmaf(res[4 * i + 0], q.x, p);
              p = fmaf(res[4 * i + 1], q.y, p);
              p = fmaf(res[4 * i + 2], q.z, p);
              p = fmaf(res[4 * i + 3], q.w, p);
            }
            p += __shfl_xor(p, 1);
            p += __shfl_xor(p, 2);
            float d = fmaf(-2.f, p, nrmAdj[j]);
            if (d < bestd || (d == bestd && j < bestj)) { bestd = d; bestj = j; }
          }
          if (kq == 0) {
            jminS[it_o] = bestj;
            const size_t ioff = (br ? OFF_RIDX : OFF_SIDX) + (size_t)(b0 + it_o) * NQL + lev;
            out[ioff] = (float)bestj;
          }
        }
      }
      __syncthreads();

      // ---- residual update + loss (exact reference rounding chain) ----
      {
        const int jm = jminS[it_o];
        const float* crow = cbf32 + ((size_t)lev * NEC + jm) * ED + kq * 64;
        float lacc = 0.f;
#pragma unroll
        for (int i = 0; i < 16; ++i) {
          float4 q = *(const float4*)(crow + 4 * i);
#pragma unroll
          for (int u = 0; u < 4; ++u) {
            float cv = (u == 0 ? q.x : u == 1 ? q.y : u == 2 ? q.z : q.w);
            float r  = res[4 * i + u];
            float dd = cv - r;
            lacc = fmaf(dd, dd, lacc);
            float xr = r + dd;      // straight-through x_res
            res[4 * i + u] = r - xr;
          }
        }
#pragma unroll
        for (int d = 1; d < 64; d <<= 1) lacc += __shfl_xor(lacc, d);
        if (lane == 0) redS[w] = lacc;
      }
      __syncthreads();
      if (tid == 0)
        atomicAdd(&lossAcc[cbi], (double)((redS[0] + redS[1]) + (redS[2] + redS[3])));
      __syncthreads();
    }

    // x_q = x - res_final (telescoped, bit-exact vs summed x_res)
    {
      const float* xp = x + (size_t)(b0 + it_o) * (2 * ED) + br * ED + kq * 64;
      float* op = out + (br ? OFF_REC : 0) + (size_t)(b0 + it_o) * ED + kq * 64;
#pragma unroll
      for (int i = 0; i < 16; ++i) {
        float4 xv = *(const float4*)(xp + 4 * i);
        float4 o;
        o.x = xv.x - res[4 * i + 0];
        o.y = xv.y - res[4 * i + 1];
        o.z = xv.z - res[4 * i + 2];
        o.w = xv.w - res[4 * i + 3];
        *(float4*)(op + 4 * i) = o;
      }
    }
    __syncthreads();
  }
}

// ---- finalize scalar loss ----
__global__ void kFin(const double* __restrict__ lossAcc, float* __restrict__ out) {
  if (blockIdx.x == 0 && threadIdx.x == 0) {
    double s = 0.0;
    for (int l = 0; l < 8; ++l) s += lossAcc[l];
    out[OFF_LOSS] = (float)(s * 1.25 / ((double)NB * ED) / 8.0);
  }
}

extern "C" void kernel_launch(void* const* d_in, const int* in_sizes, int n_in,
                              void* d_out, int out_size, void* d_ws, size_t ws_size,
                              hipStream_t stream) {
  const float* x   = (const float*)d_in[0];
  const float* cbS = (const float*)d_in[1];
  const float* cbR = (const float*)d_in[2];
  float* out = (float*)d_out;
  char*  ws  = (char*)d_ws;

  double* lossAcc = (double*)(ws + WS_LOSS);
  float*  norms   = (float*)(ws + WS_NORM);
  f16*    cbH     = (f16*)(ws + WS_CBH);

  hipLaunchKernelGGL(kPrep,  dim3(8),    dim3(256), 0, stream, cbS, cbR, norms, lossAcc);
  hipLaunchKernelGGL(kConvH, dim3(2048), dim3(256), 0, stream, cbS, cbR, cbH);
  hipLaunchKernelGGL(kMain,  dim3(NB / 64), dim3(256), 0, stream,
                     x, cbS, cbR, cbH, norms, lossAcc, out);
  hipLaunchKernelGGL(kFin,   dim3(1),    dim3(64),  0, stream, lossAcc, out);
}